// Round 13
// baseline (1025.537 us; speedup 1.0000x reference)
//
#include <hip/hip_runtime.h>
#include <hip/hip_fp16.h>

// ---------------------------------------------------------------------------
// Bidirectional 5-layer LSTM decoder, B=1024, H=32, T=200, feedback y->x.
// Round 13 = round 11 skeleton pushed to 4 waves/SIMD:
//   16 waves/block (1024 thr), wave = (d, half, t) -> ONE M-tile per wave.
//   Per-wave: 16 frags = 64 AGPR + ~55 VGPR <= 128 unified -> 4 waves/SIMD
//   (the only measured stall-filler: r10->r11 1->2 waves/SIMD = -15%).
//   Biases in LDS (r12 piece that was safe); r12's off-path acc_h and y-ring
//   REVERTED (measured net negative vs r11).
//   5 barriers/ts; Y computed redundantly on all waves (y feedback in regs).
// Weight frag layout + prep verified rounds 9-12.
// ---------------------------------------------------------------------------

#define T_STEPS 200
#define BATCH 1024

#define BIAS_OFF_B  231424            // 1280 floats [l*2+d][u][g]
#define BLIN_OFF_B  236544            // 3 floats
#define START_OFF_B 236556            // 3 floats

typedef _Float16 h2 __attribute__((ext_vector_type(2)));
typedef _Float16 half8 __attribute__((ext_vector_type(8)));
typedef float f32x4 __attribute__((ext_vector_type(4)));

__global__ __launch_bounds__(256) void prep_kernel(
    const float* __restrict__ Wih0, const float* __restrict__ Whh0,
    const float* __restrict__ bih0, const float* __restrict__ bhh0,
    const float* __restrict__ Wih,  const float* __restrict__ Whh,
    const float* __restrict__ bih,  const float* __restrict__ bhh,
    const float* __restrict__ Wlin, const float* __restrict__ blin,
    const float* __restrict__ stok, char* __restrict__ ws)
{
    int i = blockIdx.x * 256 + threadIdx.x;
    _Float16* Wo = (_Float16*)ws;
    float* biasf  = (float*)(ws + BIAS_OFF_B);
    float* blinf  = (float*)(ws + BLIN_OFF_B);
    float* startf = (float*)(ws + START_OFF_B);

    if (i < 16384) {                       // layer-0 A-frags
        int fid = i >> 9, r = i & 511;
        int lane = r >> 3, j = r & 7, q = lane >> 4, m = lane & 15;
        int kk = fid & 1, t = (fid >> 1) & 3, half = (fid >> 3) & 1, d = fid >> 4;
        int k = kk * 32 + q * 8 + j;
        int unit = half * 16 + t * 4 + (m >> 2);
        int gr = (m & 3) * 32 + unit;      // torch gate order i,f,g,o
        float v = 0.f;
        if (k < 3)       v = Wih0[(d * 128 + gr) * 3 + k];
        else if (k >= 32) v = Whh0[(d * 128 + gr) * 32 + (k - 32)];
        Wo[i] = (_Float16)v;
    } else if (i < 114688) {               // layers 1-4 A-frags
        int e = i - 16384;
        int fid = e >> 9, r = e & 511;
        int lane = r >> 3, j = r & 7, q = lane >> 4, m = lane & 15;
        int kk = fid % 3, t = (fid / 3) & 3, half = (fid / 12) & 1;
        int d = (fid / 24) & 1, l1 = fid / 48;
        int k = kk * 32 + q * 8 + j;
        int unit = half * 16 + t * 4 + (m >> 2);
        int gr = (m & 3) * 32 + unit;
        float v;
        if (k < 64) v = Wih[((l1 * 2 + d) * 128 + gr) * 64 + k];
        else        v = Whh[((l1 * 2 + d) * 128 + gr) * 32 + (k - 64)];
        Wo[i] = (_Float16)v;
    } else if (i < 115712) {               // Wlin A-frags (M rows 0..2 used)
        int e = i - 114688;
        int fid = e >> 9, r = e & 511;
        int lane = r >> 3, j = r & 7, q = lane >> 4, m = lane & 15;
        int k = fid * 32 + q * 8 + j;
        Wo[i] = (_Float16)((m < 3) ? Wlin[m * 64 + k] : 0.f);
    } else if (i < 115712 + 1280) {        // fused biases [l*2+d][u][g]
        int b = i - 115712;
        int ld = b / 128, rem = b % 128;
        int u = rem / 4, g = rem % 4;
        int gr = g * 32 + u;
        float v;
        if (ld < 2) v = bih0[ld * 128 + gr] + bhh0[ld * 128 + gr];
        else        v = bih[(ld - 2) * 128 + gr] + bhh[(ld - 2) * 128 + gr];
        biasf[b] = v;
    } else if (i < 115712 + 1280 + 3) {
        blinf[i - (115712 + 1280)] = blin[i - (115712 + 1280)];
    } else if (i < 115712 + 1280 + 6) {
        startf[i - (115712 + 1280 + 3)] = stok[i - (115712 + 1280 + 3)];
    }
}

__device__ __forceinline__ float sigm(float x)  { return 1.f / (1.f + __expf(-x)); }
__device__ __forceinline__ float tanhx(float x) { return 2.f * sigm(2.f * x) - 1.f; }
__device__ __forceinline__ unsigned short f2h_bits(float x) {
    return __builtin_bit_cast(unsigned short, (_Float16)x);
}
__device__ __forceinline__ unsigned agpr_park(unsigned v) {
    unsigned r;
    __asm__ volatile("v_accvgpr_write_b32 %0, %1" : "=a"(r) : "v"(v));
    return r;
}
__device__ __forceinline__ unsigned agpr_get(const unsigned& a) {
    unsigned r;
    __asm__ volatile("v_accvgpr_read_b32 %0, %1" : "=v"(r) : "a"(a));
    return r;
}
__device__ __forceinline__ half8 frag_of(const unsigned* a) {
    uint4 v;
    v.x = agpr_get(a[0]); v.y = agpr_get(a[1]);
    v.z = agpr_get(a[2]); v.w = agpr_get(a[3]);
    return __builtin_bit_cast(half8, v);
}

#define MFMA(A, B, C) __builtin_amdgcn_mfma_f32_16x16x32_f16((A), (B), (C), 0, 0, 0)

// per-wave frag slots (16 frags = 64 AGPR)
#define SL0(kk)     (kk)                    // 0..1
#define SL(l, kk)   (2 + ((l) - 1) * 3 + (kk))  // 2..13
#define SWL(kk)     (14 + (kk))             // 14,15

__global__ __launch_bounds__(1024) void lstm_kernel(
    const char* __restrict__ ws,
    const float* __restrict__ h0,
    const float* __restrict__ c0,
    float* __restrict__ out)
{
    const int tid  = threadIdx.x;
    const int w    = tid >> 6;
    const int d    = w & 1;           // direction
    const int half = (w >> 1) & 1;    // unit half
    const int t    = w >> 2;          // M-tile (0..3)
    const int lane = tid & 63;
    const int q    = lane >> 4;       // quad
    const int n    = lane & 15;       // batch row within block
    const int row  = blockIdx.x * 16 + n;

    __shared__ unsigned zb[6528];               // 6 regions x 16 rows x 68 words
    __shared__ __align__(16) float blds[1280];  // fused biases
    unsigned short* zh = (unsigned short*)zb;

    const uint4* gw4 = (const uint4*)ws;
    const float* biasf  = (const float*)(ws + BIAS_OFF_B);
    const float* blinf  = (const float*)(ws + BLIN_OFF_B);
    const float* startf = (const float*)(ws + START_OFF_B);

    for (int i = tid; i < 6528; i += 1024) zb[i] = 0;
    for (int i = tid; i < 1280; i += 1024) blds[i] = biasf[i];
    __syncthreads();

    // ---- park this wave's 16 A-fragments in AGPRs ----
    unsigned afr[64];
#pragma unroll
    for (int kk = 0; kk < 2; kk++) {
        uint4 v = gw4[(((d * 2 + half) * 4 + t) * 2 + kk) * 64 + lane];
        int s = SL0(kk);
        afr[4*s+0] = agpr_park(v.x); afr[4*s+1] = agpr_park(v.y);
        afr[4*s+2] = agpr_park(v.z); afr[4*s+3] = agpr_park(v.w);
    }
#pragma unroll
    for (int l1 = 0; l1 < 4; l1++)
#pragma unroll
        for (int kk = 0; kk < 3; kk++) {
            int fid = (((l1 * 2 + d) * 2 + half) * 4 + t) * 3 + kk;
            uint4 v = gw4[2048 + fid * 64 + lane];
            int s = SL(l1 + 1, kk);
            afr[4*s+0] = agpr_park(v.x); afr[4*s+1] = agpr_park(v.y);
            afr[4*s+2] = agpr_park(v.z); afr[4*s+3] = agpr_park(v.w);
        }
#pragma unroll
    for (int kk = 0; kk < 2; kk++) {
        uint4 v = gw4[14336 + kk * 64 + lane];
        int s = SWL(kk);
        afr[4*s+0] = agpr_park(v.x); afr[4*s+1] = agpr_park(v.y);
        afr[4*s+2] = agpr_park(v.z); afr[4*s+3] = agpr_park(v.w);
    }

    // ---- c-state, h-init into z-buffers ----
    float cs[5];
    const int unit = half * 16 + 4 * t + q;
#pragma unroll
    for (int l = 0; l < 5; l++) {
        int idx = ((2 * l + d) * BATCH + row) * 32 + unit;
        cs[l] = c0[idx];
        float hv = h0[idx];
        int kf = ((l == 0) ? 32 : 64) + 32 * d + unit;
        zh[(l * 16 + n) * 136 + kf] = f2h_bits(hv);
    }
    const float bl0 = blinf[0], bl1 = blinf[1], bl2 = blinf[2];
    float y0 = startf[0], y1 = startf[1], y2 = startf[2];
    __syncthreads();

#define LOADB(L, BASEK) \
    __builtin_bit_cast(half8, *(const uint4*)&zb[((L) * 16 + n) * 68 + ((BASEK) >> 1) + q * 4])
#define STH16(DL, K, HV)  zh[((DL) * 16 + n) * 136 + (K)] = f2h_bits(HV);
#define BIASV(L) (*(const f32x4*)&blds[(((L) * 2 + d) * 32 + unit) * 4])

    half8 bh0 = LOADB(0, 32 + 32 * d);   // layer-0 recurrent h (init)

    for (int ts = 0; ts < T_STEPS; ts++) {
        // ---------- SEG A: layer 0 ----------
        {
            half8 b2n_pre = LOADB(1, 64 + 32 * d);   // L1 recurrent, pre-barrier
            half8 by;
            by[0] = (q == 0) ? (_Float16)y0 : (_Float16)0.f;
            by[1] = (q == 0) ? (_Float16)y1 : (_Float16)0.f;
            by[2] = (q == 0) ? (_Float16)y2 : (_Float16)0.f;
            by[3] = (_Float16)0.f; by[4] = (_Float16)0.f;
            by[5] = (_Float16)0.f; by[6] = (_Float16)0.f; by[7] = (_Float16)0.f;
            {
                f32x4 acc = MFMA(frag_of(&afr[4 * SL0(0)]), by, BIASV(0));
                acc = MFMA(frag_of(&afr[4 * SL0(1)]), bh0, acc);
                float ii = sigm(acc[0]), ff = sigm(acc[1]);
                float gg = tanhx(acc[2]), oo = sigm(acc[3]);
                cs[0] = ff * cs[0] + ii * gg;
                float hv = oo * tanhx(cs[0]);
                STH16(1, 32 * d + unit, hv);          // layer-1 x
                STH16(0, 32 + 32 * d + unit, hv);     // own h
            }
            __syncthreads();

            // ---------- layers 1..4 ----------
            half8 b2n = b2n_pre;
#pragma unroll
            for (int l = 1; l <= 4; l++) {
                half8 b0 = LOADB(l, 0);
                half8 b1 = LOADB(l, 32);
                half8 b2 = b2n;
                {
                    f32x4 acc = MFMA(frag_of(&afr[4 * SL(l, 0)]), b0, BIASV(l));
                    acc = MFMA(frag_of(&afr[4 * SL(l, 1)]), b1, acc);
                    acc = MFMA(frag_of(&afr[4 * SL(l, 2)]), b2, acc);
                    float ii = sigm(acc[0]), ff = sigm(acc[1]);
                    float gg = tanhx(acc[2]), oo = sigm(acc[3]);
                    cs[l] = ff * cs[l] + ii * gg;
                    float hv = oo * tanhx(cs[l]);
                    STH16(((l < 4) ? (l + 1) : 5), 32 * d + unit, hv);   // next x
                    STH16(l, 64 + 32 * d + unit, hv);                     // own h
                }
                if (l < 4) b2n = LOADB(l + 1, 64 + 32 * d);   // prefetch pre-barrier
                else       bh0 = LOADB(0, 32 + 32 * d);       // next-ts layer-0 h
                __syncthreads();
            }
        }

        // ---------- Y: all waves compute y redundantly (no barrier after) ----
        {
            half8 c0f = LOADB(5, 0);
            half8 c1f = LOADB(5, 32);
            f32x4 acc = (f32x4){0.f, 0.f, 0.f, 0.f};
            acc = MFMA(frag_of(&afr[4 * SWL(0)]), c0f, acc);
            acc = MFMA(frag_of(&afr[4 * SWL(1)]), c1f, acc);
            y0 = tanhx(acc[0] + bl0);     // valid on q==0 lanes
            y1 = tanhx(acc[1] + bl1);
            y2 = tanhx(acc[2] + bl2);
            if (w == 0 && q == 0) {
                float* op = out + (ts * BATCH + row) * 3;
                op[0] = y0; op[1] = y1; op[2] = y2;
            }
        }
        // no barrier: Y reads region 5; next SEG A writes regions 0/1
        // (disjoint), and SEG-A reads are register-carried or prefetched.
    }
#undef LOADB
#undef STH16
#undef BIASV
}

extern "C" void kernel_launch(void* const* d_in, const int* in_sizes, int n_in,
                              void* d_out, int out_size, void* d_ws, size_t ws_size,
                              hipStream_t stream)
{
    const float* h0   = (const float*)d_in[0];
    const float* c0   = (const float*)d_in[1];
    const float* stok = (const float*)d_in[2];
    const float* Wih0 = (const float*)d_in[3];
    const float* Whh0 = (const float*)d_in[4];
    const float* bih0 = (const float*)d_in[5];
    const float* bhh0 = (const float*)d_in[6];
    const float* Wih  = (const float*)d_in[7];
    const float* Whh  = (const float*)d_in[8];
    const float* bih  = (const float*)d_in[9];
    const float* bhh  = (const float*)d_in[10];
    const float* Wlin = (const float*)d_in[11];
    const float* blin = (const float*)d_in[12];

    prep_kernel<<<458, 256, 0, stream>>>(Wih0, Whh0, bih0, bhh0, Wih, Whh,
                                         bih, bhh, Wlin, blin, stok, (char*)d_ws);
    lstm_kernel<<<64, 1024, 0, stream>>>((const char*)d_ws, h0, c0, (float*)d_out);
}

// Round 14
// 960.671 us; speedup vs baseline: 1.0675x; 1.0675x over previous
//
#include <hip/hip_runtime.h>
#include <hip/hip_fp16.h>

// ---------------------------------------------------------------------------
// Bidirectional 5-layer LSTM decoder, B=1024, H=32, T=200, feedback y->x.
// Round 14 = round 11 (8 waves, 2/SIMD, AGPR weights) with the per-link LDS
// pipe burst cut down (r10-r13 evidence: link cost ~2k cyc is LDS-pipe-burst
// dominated, invariant to occupancy/path tweaks):
//   - ONE unified region per layer (h_l in concat layout): x-read, recurrent
//     read and Y-read all hit the same words -> 1 store/tile (was 2), no
//     region 5. Region stride 36 words (64 halves + 8 pad), b128 reads
//     2-way-free, stores ~2-way.
//   - prefetches issued at segment TOP (before stores): in-order LDS means
//     the pre-barrier drain waits only on stores.
//   - biases in VGPRs; 5 barriers/ts; Y redundant on all waves.
// Race audit: every prefetch reads a region overwritten only in a LATER
// barrier-separated segment (S_l prefetches region l+1 h(t-1), overwritten in
// S_{l+1}; S4 prefetches region 0 h(t), overwritten in next SEG A after B5).
// ---------------------------------------------------------------------------

#define T_STEPS 200
#define BATCH 1024

#define BIAS_OFF_B  231424            // 1280 floats [l*2+d][u][g]
#define BLIN_OFF_B  236544            // 3 floats
#define START_OFF_B 236556            // 3 floats

typedef _Float16 h2 __attribute__((ext_vector_type(2)));
typedef _Float16 half8 __attribute__((ext_vector_type(8)));
typedef float f32x4 __attribute__((ext_vector_type(4)));

__global__ __launch_bounds__(256) void prep_kernel(
    const float* __restrict__ Wih0, const float* __restrict__ Whh0,
    const float* __restrict__ bih0, const float* __restrict__ bhh0,
    const float* __restrict__ Wih,  const float* __restrict__ Whh,
    const float* __restrict__ bih,  const float* __restrict__ bhh,
    const float* __restrict__ Wlin, const float* __restrict__ blin,
    const float* __restrict__ stok, char* __restrict__ ws)
{
    int i = blockIdx.x * 256 + threadIdx.x;
    _Float16* Wo = (_Float16*)ws;
    float* biasf  = (float*)(ws + BIAS_OFF_B);
    float* blinf  = (float*)(ws + BLIN_OFF_B);
    float* startf = (float*)(ws + START_OFF_B);

    if (i < 16384) {                       // layer-0 A-frags
        int fid = i >> 9, r = i & 511;
        int lane = r >> 3, j = r & 7, q = lane >> 4, m = lane & 15;
        int kk = fid & 1, t = (fid >> 1) & 3, half = (fid >> 3) & 1, d = fid >> 4;
        int k = kk * 32 + q * 8 + j;
        int unit = half * 16 + t * 4 + (m >> 2);
        int gr = (m & 3) * 32 + unit;      // torch gate order i,f,g,o
        float v = 0.f;
        if (k < 3)       v = Wih0[(d * 128 + gr) * 3 + k];
        else if (k >= 32) v = Whh0[(d * 128 + gr) * 32 + (k - 32)];
        Wo[i] = (_Float16)v;
    } else if (i < 114688) {               // layers 1-4 A-frags
        int e = i - 16384;
        int fid = e >> 9, r = e & 511;
        int lane = r >> 3, j = r & 7, q = lane >> 4, m = lane & 15;
        int kk = fid % 3, t = (fid / 3) & 3, half = (fid / 12) & 1;
        int d = (fid / 24) & 1, l1 = fid / 48;
        int k = kk * 32 + q * 8 + j;
        int unit = half * 16 + t * 4 + (m >> 2);
        int gr = (m & 3) * 32 + unit;
        float v;
        if (k < 64) v = Wih[((l1 * 2 + d) * 128 + gr) * 64 + k];
        else        v = Whh[((l1 * 2 + d) * 128 + gr) * 32 + (k - 64)];
        Wo[i] = (_Float16)v;
    } else if (i < 115712) {               // Wlin A-frags (M rows 0..2 used)
        int e = i - 114688;
        int fid = e >> 9, r = e & 511;
        int lane = r >> 3, j = r & 7, q = lane >> 4, m = lane & 15;
        int k = fid * 32 + q * 8 + j;
        Wo[i] = (_Float16)((m < 3) ? Wlin[m * 64 + k] : 0.f);
    } else if (i < 115712 + 1280) {        // fused biases [l*2+d][u][g]
        int b = i - 115712;
        int ld = b / 128, rem = b % 128;
        int u = rem / 4, g = rem % 4;
        int gr = g * 32 + u;
        float v;
        if (ld < 2) v = bih0[ld * 128 + gr] + bhh0[ld * 128 + gr];
        else        v = bih[(ld - 2) * 128 + gr] + bhh[(ld - 2) * 128 + gr];
        biasf[b] = v;
    } else if (i < 115712 + 1280 + 3) {
        blinf[i - (115712 + 1280)] = blin[i - (115712 + 1280)];
    } else if (i < 115712 + 1280 + 6) {
        startf[i - (115712 + 1280 + 3)] = stok[i - (115712 + 1280 + 3)];
    }
}

__device__ __forceinline__ float sigm(float x)  { return 1.f / (1.f + __expf(-x)); }
__device__ __forceinline__ float tanhx(float x) { return 2.f * sigm(2.f * x) - 1.f; }
__device__ __forceinline__ unsigned short f2h_bits(float x) {
    return __builtin_bit_cast(unsigned short, (_Float16)x);
}
__device__ __forceinline__ unsigned agpr_park(unsigned v) {
    unsigned r;
    __asm__ volatile("v_accvgpr_write_b32 %0, %1" : "=a"(r) : "v"(v));
    return r;
}
__device__ __forceinline__ unsigned agpr_get(const unsigned& a) {
    unsigned r;
    __asm__ volatile("v_accvgpr_read_b32 %0, %1" : "=v"(r) : "a"(a));
    return r;
}
__device__ __forceinline__ half8 frag_of(const unsigned* a) {
    uint4 v;
    v.x = agpr_get(a[0]); v.y = agpr_get(a[1]);
    v.z = agpr_get(a[2]); v.w = agpr_get(a[3]);
    return __builtin_bit_cast(half8, v);
}

#define MFMA(A, B, C) __builtin_amdgcn_mfma_f32_16x16x32_f16((A), (B), (C), 0, 0, 0)

// per-wave frag slots (30 frags = 120 AGPR)
#define SL0(tt, kk)    ((tt) * 2 + (kk))                       // 0..3
#define SL(l, tt, kk)  (4 + (((l) - 1) * 2 + (tt)) * 3 + (kk)) // 4..27
#define SWL(kk)        (28 + (kk))                             // 28,29

__global__ __launch_bounds__(512, 2) void lstm_kernel(
    const char* __restrict__ ws,
    const float* __restrict__ h0,
    const float* __restrict__ c0,
    float* __restrict__ out)
{
    const int tid  = threadIdx.x;
    const int w    = tid >> 6;
    const int d    = w & 1;           // direction
    const int half = (w >> 1) & 1;    // unit half
    const int tp   = w >> 2;          // t-pair (t = 2*tp + tt)
    const int lane = tid & 63;
    const int q    = lane >> 4;       // quad
    const int n    = lane & 15;       // batch row within block
    const int row  = blockIdx.x * 16 + n;

    // unified regions: 5 x 16 rows x 36 words (64 halves h_l concat + pad)
    __shared__ unsigned zb[2880];
    unsigned short* zh = (unsigned short*)zb;

    const uint4* gw4 = (const uint4*)ws;
    const float* biasf  = (const float*)(ws + BIAS_OFF_B);
    const float* blinf  = (const float*)(ws + BLIN_OFF_B);
    const float* startf = (const float*)(ws + START_OFF_B);

    for (int i = tid; i < 2880; i += 512) zb[i] = 0;
    __syncthreads();

    // ---- park this wave's A-fragments in AGPRs (30 frags) ----
    unsigned afr[120];
#pragma unroll
    for (int tt = 0; tt < 2; tt++)
#pragma unroll
        for (int kk = 0; kk < 2; kk++) {
            int t = 2 * tp + tt;
            uint4 v = gw4[(((d * 2 + half) * 4 + t) * 2 + kk) * 64 + lane];
            int s = SL0(tt, kk);
            afr[4*s+0] = agpr_park(v.x); afr[4*s+1] = agpr_park(v.y);
            afr[4*s+2] = agpr_park(v.z); afr[4*s+3] = agpr_park(v.w);
        }
#pragma unroll
    for (int l1 = 0; l1 < 4; l1++)
#pragma unroll
        for (int tt = 0; tt < 2; tt++)
#pragma unroll
            for (int kk = 0; kk < 3; kk++) {
                int t = 2 * tp + tt;
                int fid = (((l1 * 2 + d) * 2 + half) * 4 + t) * 3 + kk;
                uint4 v = gw4[2048 + fid * 64 + lane];
                int s = SL(l1 + 1, tt, kk);
                afr[4*s+0] = agpr_park(v.x); afr[4*s+1] = agpr_park(v.y);
                afr[4*s+2] = agpr_park(v.z); afr[4*s+3] = agpr_park(v.w);
            }
#pragma unroll
    for (int kk = 0; kk < 2; kk++) {
        uint4 v = gw4[14336 + kk * 64 + lane];
        int s = SWL(kk);
        afr[4*s+0] = agpr_park(v.x); afr[4*s+1] = agpr_park(v.y);
        afr[4*s+2] = agpr_park(v.z); afr[4*s+3] = agpr_park(v.w);
    }

    // ---- biases (VGPRs), c-state, h-init into unified regions ----
    f32x4 bias[5][2];
    float cs[5][2];
#pragma unroll
    for (int l = 0; l < 5; l++)
#pragma unroll
        for (int tt = 0; tt < 2; tt++) {
            int unit = half * 16 + 4 * (2 * tp + tt) + q;
            bias[l][tt] = *(const f32x4*)(biasf + ((l * 2 + d) * 32 + unit) * 4);
            int idx = ((2 * l + d) * BATCH + row) * 32 + unit;
            cs[l][tt] = c0[idx];
            zh[l * 1152 + n * 72 + d * 32 + unit] = f2h_bits(h0[idx]);
        }
    const float bl0 = blinf[0], bl1 = blinf[1], bl2 = blinf[2];
    float y0 = startf[0], y1 = startf[1], y2 = startf[2];
    __syncthreads();

    // LOADX(L, dd): b128 frag of region L, k-half dd (0: halves 0..31, 1: 32..63)
#define LOADX(L, DD) \
    __builtin_bit_cast(half8, *(const uint4*)&zb[(L) * 576 + n * 36 + (DD) * 16 + q * 4])
#define STH(L, UNIT, HV)  zh[(L) * 1152 + n * 72 + d * 32 + (UNIT)] = f2h_bits(HV);

    half8 bh0 = LOADX(0, d);             // layer-0 recurrent h (init)

    for (int ts = 0; ts < T_STEPS; ts++) {
        // ---------- SEG A: layer 0 (y in regs, bh0 carried) ----------
        {
            half8 b2n_pre = LOADX(1, d);             // prefetch: L1 recurrent
            half8 by;
            by[0] = (q == 0) ? (_Float16)y0 : (_Float16)0.f;
            by[1] = (q == 0) ? (_Float16)y1 : (_Float16)0.f;
            by[2] = (q == 0) ? (_Float16)y2 : (_Float16)0.f;
            by[3] = (_Float16)0.f; by[4] = (_Float16)0.f;
            by[5] = (_Float16)0.f; by[6] = (_Float16)0.f; by[7] = (_Float16)0.f;
#pragma unroll
            for (int tt = 0; tt < 2; tt++) {
                f32x4 acc = MFMA(frag_of(&afr[4 * SL0(tt, 0)]), by, bias[0][tt]);
                acc = MFMA(frag_of(&afr[4 * SL0(tt, 1)]), bh0, acc);
                float ii = sigm(acc[0]), ff = sigm(acc[1]);
                float gg = tanhx(acc[2]), oo = sigm(acc[3]);
                cs[0][tt] = ff * cs[0][tt] + ii * gg;
                float hv = oo * tanhx(cs[0][tt]);
                int unit = half * 16 + 4 * (2 * tp + tt) + q;
                STH(0, unit, hv);                    // single unified store
            }
            __syncthreads();

            // ---------- layers 1..4 ----------
            half8 b2n = b2n_pre;
#pragma unroll
            for (int l = 1; l <= 4; l++) {
                half8 b0 = LOADX(l - 1, 0);          // x = concat h_{l-1}
                half8 b1 = LOADX(l - 1, 1);
                // prefetch next recurrent BEFORE stores (drain = stores only)
                half8 nb2 = (l < 4) ? LOADX(l + 1, d) : LOADX(0, d);
                half8 b2 = b2n;
                float hv2[2];
#pragma unroll
                for (int tt = 0; tt < 2; tt++) {
                    f32x4 acc = MFMA(frag_of(&afr[4 * SL(l, tt, 0)]), b0, bias[l][tt]);
                    acc = MFMA(frag_of(&afr[4 * SL(l, tt, 1)]), b1, acc);
                    acc = MFMA(frag_of(&afr[4 * SL(l, tt, 2)]), b2, acc);
                    float ii = sigm(acc[0]), ff = sigm(acc[1]);
                    float gg = tanhx(acc[2]), oo = sigm(acc[3]);
                    cs[l][tt] = ff * cs[l][tt] + ii * gg;
                    hv2[tt] = oo * tanhx(cs[l][tt]);
                }
#pragma unroll
                for (int tt = 0; tt < 2; tt++) {
                    int unit = half * 16 + 4 * (2 * tp + tt) + q;
                    STH(l, unit, hv2[tt]);           // single unified store
                }
                if (l < 4) b2n = nb2;
                else       bh0 = nb2;                // region0 h(t) for next ts
                __syncthreads();
            }
        }

        // ---------- Y: all waves redundant, reads region 4 (no barrier) ----
        {
            half8 c0f = LOADX(4, 0);
            half8 c1f = LOADX(4, 1);
            f32x4 acc = (f32x4){0.f, 0.f, 0.f, 0.f};
            acc = MFMA(frag_of(&afr[4 * SWL(0)]), c0f, acc);
            acc = MFMA(frag_of(&afr[4 * SWL(1)]), c1f, acc);
            y0 = tanhx(acc[0] + bl0);     // valid on q==0 lanes
            y1 = tanhx(acc[1] + bl1);
            y2 = tanhx(acc[2] + bl2);
            if (w == 0 && q == 0) {
                float* op = out + (ts * BATCH + row) * 3;
                op[0] = y0; op[1] = y1; op[2] = y2;
            }
        }
        // no barrier: Y reads region 4; next SEG A writes region 0 (disjoint);
        // SEG A's operands are register-carried (y, bh0).
    }
#undef LOADX
#undef STH
}

extern "C" void kernel_launch(void* const* d_in, const int* in_sizes, int n_in,
                              void* d_out, int out_size, void* d_ws, size_t ws_size,
                              hipStream_t stream)
{
    const float* h0   = (const float*)d_in[0];
    const float* c0   = (const float*)d_in[1];
    const float* stok = (const float*)d_in[2];
    const float* Wih0 = (const float*)d_in[3];
    const float* Whh0 = (const float*)d_in[4];
    const float* bih0 = (const float*)d_in[5];
    const float* bhh0 = (const float*)d_in[6];
    const float* Wih  = (const float*)d_in[7];
    const float* Whh  = (const float*)d_in[8];
    const float* bih  = (const float*)d_in[9];
    const float* bhh  = (const float*)d_in[10];
    const float* Wlin = (const float*)d_in[11];
    const float* blin = (const float*)d_in[12];

    prep_kernel<<<458, 256, 0, stream>>>(Wih0, Whh0, bih0, bhh0, Wih, Whh,
                                         bih, bhh, Wlin, blin, stok, (char*)d_ws);
    lstm_kernel<<<64, 512, 0, stream>>>((const char*)d_ws, h0, c0, (float*)d_out);
}